// Round 13
// baseline (143.162 us; speedup 1.0000x reference)
//
#include <hip/hip_runtime.h>

typedef float  f32x4 __attribute__((ext_vector_type(4)));
typedef short  s16x8 __attribute__((ext_vector_type(8)));
typedef unsigned short u16x4 __attribute__((ext_vector_type(4)));

#define MFMA16(a,b,c) __builtin_amdgcn_mfma_f32_16x16x32_bf16(a,b,c,0,0,0)

// sizes: B=128, S=20, T=19, E=H=512, G=2048, V=10000 (padded 10112)
#define PRED_ELEMS 24320000ull

__device__ __forceinline__ unsigned short f2bf(float f){
  unsigned u = __builtin_bit_cast(unsigned, f);
  u += 0x7fffu + ((u >> 16) & 1u);
  return (unsigned short)(u >> 16);
}
__device__ __forceinline__ float sigf(float x){ return 1.0f/(1.0f + __expf(-x)); }
__device__ __forceinline__ float tanh_(float x){
  x = fminf(15.0f, fmaxf(-15.0f, x));
  float e = __expf(2.0f*x);
  return (e - 1.0f) / (e + 1.0f);
}
__device__ __forceinline__ s16x8 ld8(const unsigned short* p){
  return *reinterpret_cast<const s16x8*>(p);
}
__device__ __forceinline__ void gload_lds16(const unsigned short* src, unsigned short* dst){
  __builtin_amdgcn_global_load_lds(
      (const __attribute__((address_space(1))) void*)src,
      (__attribute__((address_space(3))) void*)dst, 16, 0, 0);
}

// ---------------- K0: stable descending sort by length, tail outputs, counter init ----------------
__global__ void k0_sort(const int* __restrict__ length, const int* __restrict__ captions,
                        float* __restrict__ out, int* __restrict__ sortp,
                        int* __restrict__ nactp, unsigned int* __restrict__ cnt4k)
{
  __shared__ int sl[128], sdl[128], ssi[128];
  int tid = threadIdx.x;
  for (int k = tid; k < 1024; k += 128) cnt4k[k] = 0u;   // claim counters + arrival flags (4 KB)
  if (tid < 128) sl[tid] = length[tid];
  __syncthreads();
  if (tid < 128){
    int l = sl[tid];
    int rank = 0;
    for (int j = 0; j < 128; ++j){
      int lj = sl[j];
      rank += (lj > l) || (lj == l && j < tid);
    }
    sortp[rank] = tid;
    ssi[rank] = tid;   sdl[rank] = l - 1;
  }
  __syncthreads();
  if (tid < 20){
    int c = 0;
    for (int r = 0; r < 128; ++r) c += (sdl[r] >= tid);
    nactp[tid] = c;
  }
  if (tid < 128){
    const size_t P = PRED_ELEMS;
    int si = ssi[tid];
    for (int t = 0; t < 20; ++t) out[P + tid*20 + t] = (float)captions[si*20 + t];
    out[P + 2560 + tid] = (float)sdl[tid];
    out[P + 2688 + tid] = (float)si;
  }
}

// ---------------- K1: bf16 conversion / gather / zero-init (4-elem units) ----------------
__device__ __forceinline__ void cvt4(unsigned short* dst, const float* src, int u){
  f32x4 v = *reinterpret_cast<const f32x4*>(src + (size_t)u*4);
  u16x4 o;
  o[0]=f2bf(v[0]); o[1]=f2bf(v[1]); o[2]=f2bf(v[2]); o[3]=f2bf(v[3]);
  *reinterpret_cast<u16x4*>(dst + (size_t)u*4) = o;
}

__global__ void k1_convert(const float* __restrict__ images, const int* __restrict__ captions,
    const float* __restrict__ emb, const float* __restrict__ wih, const float* __restrict__ whh,
    const float* __restrict__ bih, const float* __restrict__ bhh, const float* __restrict__ fcw,
    const int* __restrict__ sortp,
    unsigned short* __restrict__ wihb, unsigned short* __restrict__ whhb,
    unsigned short* __restrict__ fcwb, float* __restrict__ biasp,
    unsigned short* __restrict__ xseq, unsigned short* __restrict__ hseq,
    unsigned short* __restrict__ hloc)
{
  const int U0 = 262144;      // W_ih  2048*512/4
  const int U1 = 262144;      // W_hh
  const int U2 = 1294336;     // fc_w padded 10112*512/4
  const int U3 = 512;         // bias 2048/4
  const int U4 = 327680;      // xseq 20*128*512/4
  const int U5 = 16384;       // hseq canonical slot 0 (zero h_init)
  const int U6 = 16384;       // hloc slot 0 per XCD (8 x 16 x 512)
  const int total = U0+U1+U2+U3+U4+U5+U6;
  for (int i = blockIdx.x*blockDim.x + threadIdx.x; i < total; i += gridDim.x*blockDim.x){
    int j = i;
    if (j < U0){ cvt4(wihb, wih, j); continue; }
    j -= U0;
    if (j < U1){ cvt4(whhb, whh, j); continue; }
    j -= U1;
    if (j < U2){
      int row = j >> 7;               // (j*4)/512
      if (row < 10000) cvt4(fcwb, fcw, j);
      else { u16x4 z = {0,0,0,0}; *reinterpret_cast<u16x4*>(fcwb + (size_t)j*4) = z; }
      continue;
    }
    j -= U2;
    if (j < U3){
      int e0 = j*4;
      for (int e = 0; e < 4; ++e) biasp[e0+e] = bih[e0+e] + bhh[e0+e];
      continue;
    }
    j -= U3;
    if (j < U4){
      int elem = j*4;
      int s = elem >> 16;             // /65536
      int rem = elem & 65535;
      int r = rem >> 9;
      int k = rem & 511;
      const float* src;
      if (s == 0) src = images + (size_t)sortp[r]*512 + k;
      else {
        int cap = captions[sortp[r]*20 + (s-1)];
        src = emb + (size_t)cap*512 + k;
      }
      f32x4 v = *reinterpret_cast<const f32x4*>(src);
      u16x4 o;
      o[0]=f2bf(v[0]); o[1]=f2bf(v[1]); o[2]=f2bf(v[2]); o[3]=f2bf(v[3]);
      *reinterpret_cast<u16x4*>(xseq + (size_t)j*4) = o;
      continue;
    }
    j -= U4;
    if (j < U5){ u16x4 z = {0,0,0,0}; *reinterpret_cast<u16x4*>(hseq + (size_t)j*4) = z; continue; }
    j -= U5;
    { // hloc slot 0 per XCD: hloc[x][0][16][512]
      int e0 = j*4;
      int x = e0 >> 13;               // /8192 (16*512)
      int rem = e0 & 8191;
      u16x4 z = {0,0,0,0};
      *reinterpret_cast<u16x4*>(hloc + (size_t)x*172032 + rem) = z;  // 21*16*512 per XCD
    }
  }
}

// ---------------- K3: XCD-local persistent LSTM chain, L2-local asm-atomic barrier ----------------
// 256 blocks x 256 threads, ~148 KB LDS -> 1 block/CU -> 32 blocks/XCD (capacity-
// forced). Both weight slices in LDS. Per-step barrier entirely in the XCD's own L2:
// arrival = asm global_atomic_swap (no sc bits -> executes in local L2), poll = asm
// global_atomic_add 0 with sc0 (atomic-with-return; atomics always execute at L2,
// never L1 -> no staleness; inline asm is opaque to the compiler -> no r10-style
// hoisting). Flags zeroed by k0 (dispatch-end writeback makes them globally 0);
// each XCD touches only its own 256B flag stripe. ax (x-part A-frags) prefetched
// for s+1 during the spin; accx/acch split so x-MFMAs issue before h loads land.
__global__ __launch_bounds__(256) void lstm_chain(
    const unsigned short* __restrict__ xseq, const unsigned short* __restrict__ wih,
    const unsigned short* __restrict__ whh, const float* __restrict__ biasp,
    unsigned short* __restrict__ hseq, unsigned short* __restrict__ hloc,
    const int* __restrict__ nact, unsigned int* __restrict__ claimc,
    unsigned int* __restrict__ flags)
{
  const int tid = threadIdx.x;
  __shared__ int s_xw;
  __shared__ unsigned short WIl[64*524];    // 67.1 KB W_ih slice
  __shared__ unsigned short WHl[64*524];    // 67.1 KB W_hh slice
  __shared__ float pg[4][4][16][17];        // 17.4 KB partial gates (kk, q, row, col)

  if (tid == 0){
    unsigned xcc;
    asm volatile("s_getreg_b32 %0, hwreg(20, 0, 4)" : "=s"(xcc));  // HW_REG_XCC_ID
    int x = (int)(xcc & 7u);
    unsigned slot = __hip_atomic_fetch_add(claimc + x*64, 1u,
                      __ATOMIC_RELAXED, __HIP_MEMORY_SCOPE_AGENT);
    s_xw = (x << 8) | (int)(slot & 255u);
  }
  __syncthreads();
  const int x = s_xw >> 8;
  const int w = s_xw & 255;
  if (w >= 32) return;
  const int R0 = x*16;
  const int C0 = w*16;
  unsigned int* myflags = flags + x*64;     // 32 words used per XCD, 256B stride

  const int lane = tid & 63;
  const int kk   = tid >> 6;                 // wave = k-quarter (128 of 512)
  const int fr   = lane & 15;
  const int fkq  = (lane >> 4) * 8;

  // preload both weight slices: local row lr=q*16+jj <-> weight row q*512 + C0 + jj
  for (int idx = tid; idx < 64*64; idx += 256){
    int lr = idx >> 6, kc = (idx & 63)*8;
    int q = lr >> 4, jj = lr & 15;
    size_t off = (size_t)(q*512 + C0 + jj)*512 + kc;
    *reinterpret_cast<s16x8*>(&WIl[lr*524 + kc]) = ld8(wih + off);
    *reinterpret_cast<s16x8*>(&WHl[lr*524 + kc]) = ld8(whh + off);
  }

  unsigned short* hl = hloc + (size_t)x*172032;   // [21][16][512]
  const int prow = tid >> 4;
  const int pcol = tid & 15;
  const float bz0 = biasp[       C0 + pcol];
  const float bz1 = biasp[ 512 + C0 + pcol];
  const float bz2 = biasp[1024 + C0 + pcol];
  const float bz3 = biasp[1536 + C0 + pcol];
  float creg = 0.f;

  // prefetch x-part A fragments for step 0
  s16x8 ax[4];
  #pragma unroll
  for (int i = 0; i < 4; ++i)
    ax[i] = ld8(xseq + (R0 + fr)*512 + kk*128 + i*32 + fkq);
  __syncthreads();

  for (int s = 0; s < 20; ++s){
    if (R0 >= nact[s]) break;
    const unsigned short* hp = hl + (size_t)s*8192;

    s16x8 ah[4];
    #pragma unroll
    for (int i = 0; i < 4; ++i)
      ah[i] = ld8(hp + fr*512 + kk*128 + i*32 + fkq);

    // partial gates: x-chain independent of h-loads (accx), then h-chain (acch)
    #pragma unroll
    for (int q = 0; q < 4; ++q){
      f32x4 accx = (f32x4){0.f,0.f,0.f,0.f};
      f32x4 acch = (f32x4){0.f,0.f,0.f,0.f};
      #pragma unroll
      for (int i = 0; i < 4; ++i){
        s16x8 bi = *reinterpret_cast<const s16x8*>(&WIl[(q*16 + fr)*524 + kk*128 + i*32 + fkq]);
        accx = MFMA16(ax[i], bi, accx);
      }
      #pragma unroll
      for (int i = 0; i < 4; ++i){
        s16x8 bh = *reinterpret_cast<const s16x8*>(&WHl[(q*16 + fr)*524 + kk*128 + i*32 + fkq]);
        acch = MFMA16(ah[i], bh, acch);
      }
      const int rr = (lane >> 4) * 4;
      #pragma unroll
      for (int p = 0; p < 4; ++p)
        pg[kk][q][rr + p][fr] = accx[p] + acch[p];
    }
    __syncthreads();

    unsigned short hb;
    {
      float iv = pg[0][0][prow][pcol] + pg[1][0][prow][pcol]
               + pg[2][0][prow][pcol] + pg[3][0][prow][pcol] + bz0;
      float fv = pg[0][1][prow][pcol] + pg[1][1][prow][pcol]
               + pg[2][1][prow][pcol] + pg[3][1][prow][pcol] + bz1;
      float gv = pg[0][2][prow][pcol] + pg[1][2][prow][pcol]
               + pg[2][2][prow][pcol] + pg[3][2][prow][pcol] + bz2;
      float ov = pg[0][3][prow][pcol] + pg[1][3][prow][pcol]
               + pg[2][3][prow][pcol] + pg[3][3][prow][pcol] + bz3;
      creg = sigf(fv)*creg + sigf(iv)*tanh_(gv);
      float h = sigf(ov)*tanh_(creg);
      hb = f2bf(h);
      hl[(size_t)(s+1)*8192 + prow*512 + C0 + pcol] = hb;   // XCD-local publish
    }
    __syncthreads();   // drains vmcnt: hl stores acked in this XCD's L2; protects pg

    // canonical mirror for fc — off the critical path (consumed after dispatch release)
    hseq[(size_t)(s+1)*65536 + (R0 + prow)*512 + C0 + pcol] = hb;

    if (s < 19 && nact[s+1] > R0){
      const unsigned tgt = (unsigned)(s + 1);
      // prefetch ax for next step during the spin (x-part is barrier-independent)
      const unsigned short* xp = xseq + (size_t)(s+1)*65536;
      #pragma unroll
      for (int i = 0; i < 4; ++i)
        ax[i] = ld8(xp + (R0 + fr)*512 + kk*128 + i*32 + fkq);

      if (tid == 0){
        unsigned int* fa = myflags + w;
        asm volatile("global_atomic_swap %0, %1, off"
                     :: "v"(fa), "v"(tgt) : "memory");       // arrival: local-L2 atomic
      }
      if (tid < 64){
        unsigned int* pa = myflags + (tid & 31);
        long guard = 0;
        for (;;){
          bool ok = true;
          if (tid < 32){
            unsigned old;
            asm volatile("global_atomic_add %0, %1, %2, off sc0\n\t"
                         "s_waitcnt vmcnt(0)"
                         : "=v"(old) : "v"(pa), "v"(0u) : "memory");
            ok = (old >= tgt);
          }
          if (__all(ok) || ++guard > (1L << 20)) break;
          __builtin_amdgcn_s_sleep(1);
        }
      }
      __syncthreads();
    }
  }
}

// ---------------- K4: batched FC, m97-style global_load_lds dbuf + XOR swizzle ----------------
__global__ __launch_bounds__(256) void fc_kernel(
    const unsigned short* __restrict__ hseq, const unsigned short* __restrict__ fcwb,
    const float* __restrict__ fcb, const int* __restrict__ nact,
    float* __restrict__ out)
{
  const int b    = blockIdx.x;
  const int x    = b & 7;
  const int slot = b >> 3;
  const int t    = slot % 19;
  const int p    = x + 8*(slot/19);
  if (p >= 79) return;
  const int v0   = p * 128;
  const int tid  = threadIdx.x;

  __shared__ unsigned short Ab[2][128*64];   // 16 KB each
  __shared__ unsigned short Bb[2][128*64];

  const unsigned short* Ag = hseq + (size_t)(t + 2)*65536;   // h_{t+1}: 128 x 512
  const unsigned short* Bg = fcwb + (size_t)v0*512;          // panel: 128 x 512
  const int n_t = nact[t + 1];

  const int srow = tid >> 3;          // 0..31
  const int sphy = tid & 7;
  const int wuni = (tid >> 6) << 9;   // wave-uniform LDS base (elements): wave*512

  #define STAGE(gsrc, lbuf, kt)                                              \
    _Pragma("unroll")                                                        \
    for (int call = 0; call < 4; ++call){                                    \
      int row_ = call*32 + srow;                                             \
      gload_lds16(gsrc + (size_t)row_*512 + (kt)*64 + ((sphy ^ (row_ & 7)) << 3), \
                  lbuf + call*2048 + wuni);                                  \
    }

  const int lane = tid & 63;
  const int wv   = tid >> 6;
  const int wr   = wv >> 1, wc = wv & 1;
  const int fr   = lane & 15;
  const int hi   = lane >> 4;         // 0..3

  f32x4 acc[4][4];
  #pragma unroll
  for (int i = 0; i < 4; ++i)
    #pragma unroll
    for (int j = 0; j < 4; ++j)
      acc[i][j] = (f32x4){0.f,0.f,0.f,0.f};

  STAGE(Ag, Ab[0], 0)
  STAGE(Bg, Bb[0], 0)
  asm volatile("s_waitcnt vmcnt(0)" ::: "memory");
  __syncthreads();

  int cur = 0;
  for (int kt = 0; kt < 8; ++kt){
    if (kt < 7){
      STAGE(Ag, Ab[cur^1], kt+1)
      STAGE(Bg, Bb[cur^1], kt+1)
    }
    const unsigned short* As = Ab[cur];
    const unsigned short* Bs = Bb[cur];
    #pragma unroll
    for (int kk = 0; kk < 2; ++kk){
      const int c = kk*4 + hi;        // logical 16B slot within 64-elem row
      s16x8 af[4], bf[4];
      #pragma unroll
      for (int i = 0; i < 4; ++i){
        int row = wr*64 + i*16 + fr;
        af[i] = ld8(As + row*64 + ((c ^ (row & 7)) << 3));
      }
      #pragma unroll
      for (int j = 0; j < 4; ++j){
        int col = wc*64 + j*16 + fr;
        bf[j] = ld8(Bs + col*64 + ((c ^ (col & 7)) << 3));
      }
      #pragma unroll
      for (int i = 0; i < 4; ++i)
        #pragma unroll
        for (int j = 0; j < 4; ++j)
          acc[i][j] = MFMA16(af[i], bf[j], acc[i][j]);
    }
    asm volatile("s_waitcnt vmcnt(0)" ::: "memory");
    __syncthreads();
    cur ^= 1;
  }

  const int rr = hi * 4;
  #pragma unroll
  for (int j = 0; j < 4; ++j){
    int v = v0 + wc*64 + j*16 + fr;
    if (v >= 10000) continue;
    float bb = fcb[v];
    #pragma unroll
    for (int i = 0; i < 4; ++i){
      #pragma unroll
      for (int pp = 0; pp < 4; ++pp){
        int r = wr*64 + i*16 + rr + pp;
        out[(size_t)(r*19 + t)*10000 + v] = (r < n_t) ? (acc[i][j][pp] + bb) : 0.0f;
      }
    }
  }
  #undef STAGE
}

extern "C" void kernel_launch(void* const* d_in, const int* in_sizes, int n_in,
                              void* d_out, int out_size, void* d_ws, size_t ws_size,
                              hipStream_t stream) {
  const float* images   = (const float*)d_in[0];
  const int*   captions = (const int*)  d_in[1];
  const int*   length   = (const int*)  d_in[2];
  const float* emb      = (const float*)d_in[3];
  const float* W_ih     = (const float*)d_in[4];
  const float* W_hh     = (const float*)d_in[5];
  const float* b_ih     = (const float*)d_in[6];
  const float* b_hh     = (const float*)d_in[7];
  const float* fc_w     = (const float*)d_in[8];
  const float* fc_b     = (const float*)d_in[9];
  float* out = (float*)d_out;
  char*  ws  = (char*)d_ws;

  int*            sortp  = (int*)           (ws + 0);
  int*            nactp  = (int*)           (ws + 2048);
  float*          biasp  = (float*)         (ws + 4096);
  unsigned int*   cnt4k  = (unsigned int*)  (ws + 12288);     // claim[8] + flags[8][32]
  unsigned int*   claimc = cnt4k;                              // claimc + x*64
  unsigned int*   flags  = cnt4k + 512;                        // flags + x*64 + w
  unsigned short* hloc   = (unsigned short*)(ws + 16384);      // 8 x [21][16][512] bf16
  unsigned short* hseq   = (unsigned short*)(ws + 2768896);    // canonical 21 x 128 x 512 bf16
  unsigned short* xseq   = (unsigned short*)(ws + 5521408);    // 20 slots
  unsigned short* wihb   = (unsigned short*)(ws + 8142848);
  unsigned short* whhb   = (unsigned short*)(ws + 10240000);
  unsigned short* fcwb   = (unsigned short*)(ws + 12337152);   // 10112x512 bf16, ends ~22.7 MB

  k0_sort<<<1, 128, 0, stream>>>(length, captions, out, sortp, nactp, cnt4k);
  k1_convert<<<4096, 256, 0, stream>>>(images, captions, emb, W_ih, W_hh, b_ih, b_hh,
                                       fc_w, sortp, wihb, whhb, fcwb, biasp, xseq, hseq, hloc);
  lstm_chain<<<256, 256, 0, stream>>>(xseq, wihb, whhb, biasp, hseq, hloc,
                                      nactp, claimc, flags);
  fc_kernel<<<1520, 256, 0, stream>>>(hseq, fcwb, fc_b, nactp, out);
}

// Round 14
// 122.896 us; speedup vs baseline: 1.1649x; 1.1649x over previous
//
#include <hip/hip_runtime.h>

typedef float  f32x4 __attribute__((ext_vector_type(4)));
typedef short  s16x8 __attribute__((ext_vector_type(8)));
typedef unsigned short u16x4 __attribute__((ext_vector_type(4)));

#define MFMA16(a,b,c) __builtin_amdgcn_mfma_f32_16x16x32_bf16(a,b,c,0,0,0)

// sizes: B=128, S=20, T=19, E=H=512, G=2048, V=10000 (padded 10112)
#define PRED_ELEMS 24320000ull

__device__ __forceinline__ unsigned short f2bf(float f){
  unsigned u = __builtin_bit_cast(unsigned, f);
  u += 0x7fffu + ((u >> 16) & 1u);
  return (unsigned short)(u >> 16);
}
__device__ __forceinline__ float sigf(float x){ return 1.0f/(1.0f + __expf(-x)); }
__device__ __forceinline__ float tanh_(float x){
  x = fminf(15.0f, fmaxf(-15.0f, x));
  float e = __expf(2.0f*x);
  return (e - 1.0f) / (e + 1.0f);
}
__device__ __forceinline__ s16x8 ld8(const unsigned short* p){
  return *reinterpret_cast<const s16x8*>(p);
}
__device__ __forceinline__ void gload_lds16(const unsigned short* src, unsigned short* dst){
  __builtin_amdgcn_global_load_lds(
      (const __attribute__((address_space(1))) void*)src,
      (__attribute__((address_space(3))) void*)dst, 16, 0, 0);
}

// ---------------- K0: stable descending sort by length, tail outputs, counter init ----------------
__global__ void k0_sort(const int* __restrict__ length, const int* __restrict__ captions,
                        float* __restrict__ out, int* __restrict__ sortp,
                        int* __restrict__ nactp, unsigned int* __restrict__ cnt4k)
{
  __shared__ int sl[128], sdl[128], ssi[128];
  int tid = threadIdx.x;
  for (int k = tid; k < 1024; k += 128) cnt4k[k] = 0u;   // claim counters + arrival flags (4 KB)
  if (tid < 128) sl[tid] = length[tid];
  __syncthreads();
  if (tid < 128){
    int l = sl[tid];
    int rank = 0;
    for (int j = 0; j < 128; ++j){
      int lj = sl[j];
      rank += (lj > l) || (lj == l && j < tid);
    }
    sortp[rank] = tid;
    ssi[rank] = tid;   sdl[rank] = l - 1;
  }
  __syncthreads();
  if (tid < 20){
    int c = 0;
    for (int r = 0; r < 128; ++r) c += (sdl[r] >= tid);
    nactp[tid] = c;
  }
  if (tid < 128){
    const size_t P = PRED_ELEMS;
    int si = ssi[tid];
    for (int t = 0; t < 20; ++t) out[P + tid*20 + t] = (float)captions[si*20 + t];
    out[P + 2560 + tid] = (float)sdl[tid];
    out[P + 2688 + tid] = (float)si;
  }
}

// ---------------- K1: bf16 conversion / gather / zero-init (4-elem units) ----------------
__device__ __forceinline__ void cvt4(unsigned short* dst, const float* src, int u){
  f32x4 v = *reinterpret_cast<const f32x4*>(src + (size_t)u*4);
  u16x4 o;
  o[0]=f2bf(v[0]); o[1]=f2bf(v[1]); o[2]=f2bf(v[2]); o[3]=f2bf(v[3]);
  *reinterpret_cast<u16x4*>(dst + (size_t)u*4) = o;
}

__global__ void k1_convert(const float* __restrict__ images, const int* __restrict__ captions,
    const float* __restrict__ emb, const float* __restrict__ wih, const float* __restrict__ whh,
    const float* __restrict__ bih, const float* __restrict__ bhh, const float* __restrict__ fcw,
    const int* __restrict__ sortp,
    unsigned short* __restrict__ wihb, unsigned short* __restrict__ whhb,
    unsigned short* __restrict__ fcwb, float* __restrict__ biasp,
    unsigned short* __restrict__ xseq, unsigned short* __restrict__ hseq,
    unsigned short* __restrict__ hloc)
{
  const int U0 = 262144;      // W_ih  2048*512/4
  const int U1 = 262144;      // W_hh
  const int U2 = 1294336;     // fc_w padded 10112*512/4
  const int U3 = 512;         // bias 2048/4
  const int U4 = 327680;      // xseq 20*128*512/4
  const int U5 = 16384;       // hseq canonical slot 0 (zero h_init)
  const int U6 = 16384;       // hloc slot 0 per XCD (8 x 16 x 512)
  const int total = U0+U1+U2+U3+U4+U5+U6;
  for (int i = blockIdx.x*blockDim.x + threadIdx.x; i < total; i += gridDim.x*blockDim.x){
    int j = i;
    if (j < U0){ cvt4(wihb, wih, j); continue; }
    j -= U0;
    if (j < U1){ cvt4(whhb, whh, j); continue; }
    j -= U1;
    if (j < U2){
      int row = j >> 7;               // (j*4)/512
      if (row < 10000) cvt4(fcwb, fcw, j);
      else { u16x4 z = {0,0,0,0}; *reinterpret_cast<u16x4*>(fcwb + (size_t)j*4) = z; }
      continue;
    }
    j -= U2;
    if (j < U3){
      int e0 = j*4;
      for (int e = 0; e < 4; ++e) biasp[e0+e] = bih[e0+e] + bhh[e0+e];
      continue;
    }
    j -= U3;
    if (j < U4){
      int elem = j*4;
      int s = elem >> 16;             // /65536
      int rem = elem & 65535;
      int r = rem >> 9;
      int k = rem & 511;
      const float* src;
      if (s == 0) src = images + (size_t)sortp[r]*512 + k;
      else {
        int cap = captions[sortp[r]*20 + (s-1)];
        src = emb + (size_t)cap*512 + k;
      }
      f32x4 v = *reinterpret_cast<const f32x4*>(src);
      u16x4 o;
      o[0]=f2bf(v[0]); o[1]=f2bf(v[1]); o[2]=f2bf(v[2]); o[3]=f2bf(v[3]);
      *reinterpret_cast<u16x4*>(xseq + (size_t)j*4) = o;
      continue;
    }
    j -= U4;
    if (j < U5){ u16x4 z = {0,0,0,0}; *reinterpret_cast<u16x4*>(hseq + (size_t)j*4) = z; continue; }
    j -= U5;
    { // hloc slot 0 per XCD: hloc[x][0][16][512]
      int e0 = j*4;
      int x = e0 >> 13;               // /8192 (16*512)
      int rem = e0 & 8191;
      u16x4 z = {0,0,0,0};
      *reinterpret_cast<u16x4*>(hloc + (size_t)x*172032 + rem) = z;  // 21*16*512 per XCD
    }
  }
}

// ---------------- K3: XCD-local persistent LSTM chain, weights-in-registers, ----------------
// x-GEMM hidden inside the barrier window.
// 256 blocks x 256 threads, ~86 KB LDS (incl. pinned pad) -> 1 block/CU -> 32 blocks/XCD.
// Step-invariant B-fragments (W_ih, W_hh: 32 frags = 128 VGPR) live in registers ->
// per-step critical path is {16 ah loads -> 16 MFMA -> pg write -> pointwise}.
// x-partials for step s+1 are computed BETWEEN flag-store and spin (barrier slack).
// Barrier: r12-proven flag store + wave-parallel relaxed poll, agent scope.
__global__ __launch_bounds__(256, 1) void lstm_chain(
    const unsigned short* __restrict__ xseq, const unsigned short* __restrict__ wih,
    const unsigned short* __restrict__ whh, const float* __restrict__ biasp,
    unsigned short* __restrict__ hseq, unsigned short* __restrict__ hloc,
    const int* __restrict__ nact, unsigned int* __restrict__ claimc,
    unsigned int* __restrict__ flags)
{
  const int tid = threadIdx.x;
  __shared__ int s_xw;
  __shared__ float pgh[4][4][16][17];       // 17.4 KB h-partials (kk, q, row, col)
  __shared__ float pgx[4][4][16][17];       // 17.4 KB x-partials for next step
  __shared__ unsigned char lds_pad[51200];  // pin LDS > 80 KB -> capacity-forced 1 block/CU
  asm volatile("" : : "v"(&lds_pad[tid & 127]) : "memory");

  if (tid == 0){
    unsigned xcc;
    asm volatile("s_getreg_b32 %0, hwreg(20, 0, 4)" : "=s"(xcc));  // HW_REG_XCC_ID
    int x = (int)(xcc & 7u);
    unsigned slot = __hip_atomic_fetch_add(claimc + x*64, 1u,
                      __ATOMIC_RELAXED, __HIP_MEMORY_SCOPE_AGENT);
    s_xw = (x << 8) | (int)(slot & 255u);
  }
  __syncthreads();
  const int x = s_xw >> 8;
  const int w = s_xw & 255;
  if (w >= 32) return;
  const int R0 = x*16;
  const int C0 = w*16;
  unsigned int* myflags = flags + x*64;     // 32 words used per XCD, 256B stride

  const int lane = tid & 63;
  const int kk   = tid >> 6;                 // wave = k-quarter (128 of 512)
  const int fr   = lane & 15;
  const int fkq  = (lane >> 4) * 8;
  const int rr   = (lane >> 4) * 4;

  // step-invariant B fragments in registers: [gate][k-chunk]
  s16x8 BI[4][4], BH[4][4];
  #pragma unroll
  for (int q = 0; q < 4; ++q)
    #pragma unroll
    for (int i = 0; i < 4; ++i){
      size_t off = (size_t)(q*512 + C0 + fr)*512 + kk*128 + i*32 + fkq;
      BI[q][i] = ld8(wih + off);
      BH[q][i] = ld8(whh + off);
    }

  unsigned short* hl = hloc + (size_t)x*172032;   // [21][16][512]
  const int prow = tid >> 4;
  const int pcol = tid & 15;
  const float bz0 = biasp[       C0 + pcol];
  const float bz1 = biasp[ 512 + C0 + pcol];
  const float bz2 = biasp[1024 + C0 + pcol];
  const float bz3 = biasp[1536 + C0 + pcol];
  float creg = 0.f;

  // prologue: x-partials for step 0
  {
    s16x8 ax[4];
    #pragma unroll
    for (int i = 0; i < 4; ++i)
      ax[i] = ld8(xseq + (R0 + fr)*512 + kk*128 + i*32 + fkq);
    #pragma unroll
    for (int q = 0; q < 4; ++q){
      f32x4 accx = (f32x4){0.f,0.f,0.f,0.f};
      #pragma unroll
      for (int i = 0; i < 4; ++i)
        accx = MFMA16(ax[i], BI[q][i], accx);
      #pragma unroll
      for (int p = 0; p < 4; ++p)
        pgx[kk][q][rr + p][fr] = accx[p];
    }
  }
  __syncthreads();

  for (int s = 0; s < 20; ++s){
    if (R0 >= nact[s]) break;
    const unsigned short* hp = hl + (size_t)s*8192;

    // h-part: 16 loads, 16 MFMAs, B from registers
    s16x8 ah[4];
    #pragma unroll
    for (int i = 0; i < 4; ++i)
      ah[i] = ld8(hp + fr*512 + kk*128 + i*32 + fkq);
    #pragma unroll
    for (int q = 0; q < 4; ++q){
      f32x4 acch = (f32x4){0.f,0.f,0.f,0.f};
      #pragma unroll
      for (int i = 0; i < 4; ++i)
        acch = MFMA16(ah[i], BH[q][i], acch);
      #pragma unroll
      for (int p = 0; p < 4; ++p)
        pgh[kk][q][rr + p][fr] = acch[p];
    }
    __syncthreads();   // (A) pgh ready; pgx from previous window ready

    unsigned short hb;
    {
      float iv = pgh[0][0][prow][pcol] + pgh[1][0][prow][pcol]
               + pgh[2][0][prow][pcol] + pgh[3][0][prow][pcol]
               + pgx[0][0][prow][pcol] + pgx[1][0][prow][pcol]
               + pgx[2][0][prow][pcol] + pgx[3][0][prow][pcol] + bz0;
      float fv = pgh[0][1][prow][pcol] + pgh[1][1][prow][pcol]
               + pgh[2][1][prow][pcol] + pgh[3][1][prow][pcol]
               + pgx[0][1][prow][pcol] + pgx[1][1][prow][pcol]
               + pgx[2][1][prow][pcol] + pgx[3][1][prow][pcol] + bz1;
      float gv = pgh[0][2][prow][pcol] + pgh[1][2][prow][pcol]
               + pgh[2][2][prow][pcol] + pgh[3][2][prow][pcol]
               + pgx[0][2][prow][pcol] + pgx[1][2][prow][pcol]
               + pgx[2][2][prow][pcol] + pgx[3][2][prow][pcol] + bz2;
      float ov = pgh[0][3][prow][pcol] + pgh[1][3][prow][pcol]
               + pgh[2][3][prow][pcol] + pgh[3][3][prow][pcol]
               + pgx[0][3][prow][pcol] + pgx[1][3][prow][pcol]
               + pgx[2][3][prow][pcol] + pgx[3][3][prow][pcol] + bz3;
      creg = sigf(fv)*creg + sigf(iv)*tanh_(gv);
      float h = sigf(ov)*tanh_(creg);
      hb = f2bf(h);
      hl[(size_t)(s+1)*8192 + prow*512 + C0 + pcol] = hb;   // XCD-local publish
    }
    __syncthreads();   // (B) hl drained into this XCD's L2; pgx consumed

    // canonical mirror for fc — off the critical path (consumed after dispatch release)
    hseq[(size_t)(s+1)*65536 + (R0 + prow)*512 + C0 + pcol] = hb;

    if (s < 19 && nact[s+1] > R0){
      const unsigned tgt = (unsigned)(s + 1);
      if (tid == 0)
        __hip_atomic_store(&myflags[w], tgt, __ATOMIC_RELAXED, __HIP_MEMORY_SCOPE_AGENT);

      // x-partials for step s+1 — useful work inside the barrier window
      {
        const unsigned short* xp = xseq + (size_t)(s+1)*65536;
        s16x8 ax[4];
        #pragma unroll
        for (int i = 0; i < 4; ++i)
          ax[i] = ld8(xp + (R0 + fr)*512 + kk*128 + i*32 + fkq);
        #pragma unroll
        for (int q = 0; q < 4; ++q){
          f32x4 accx = (f32x4){0.f,0.f,0.f,0.f};
          #pragma unroll
          for (int i = 0; i < 4; ++i)
            accx = MFMA16(ax[i], BI[q][i], accx);
          #pragma unroll
          for (int p = 0; p < 4; ++p)
            pgx[kk][q][rr + p][fr] = accx[p];
        }
      }

      if (tid < 64){
        long guard = 0;
        for (;;){
          bool ok = true;
          if (tid < 32)
            ok = (__hip_atomic_load(&myflags[tid], __ATOMIC_RELAXED,
                                    __HIP_MEMORY_SCOPE_AGENT) >= tgt);
          if (__all(ok) || ++guard > (1L << 20)) break;
          __builtin_amdgcn_s_sleep(1);
        }
      }
      __syncthreads();   // (C) release
    }
  }
}

// ---------------- K4: batched FC, m97-style global_load_lds dbuf + XOR swizzle ----------------
__global__ __launch_bounds__(256) void fc_kernel(
    const unsigned short* __restrict__ hseq, const unsigned short* __restrict__ fcwb,
    const float* __restrict__ fcb, const int* __restrict__ nact,
    float* __restrict__ out)
{
  const int b    = blockIdx.x;
  const int x    = b & 7;
  const int slot = b >> 3;
  const int t    = slot % 19;
  const int p    = x + 8*(slot/19);
  if (p >= 79) return;
  const int v0   = p * 128;
  const int tid  = threadIdx.x;

  __shared__ unsigned short Ab[2][128*64];   // 16 KB each
  __shared__ unsigned short Bb[2][128*64];

  const unsigned short* Ag = hseq + (size_t)(t + 2)*65536;   // h_{t+1}: 128 x 512
  const unsigned short* Bg = fcwb + (size_t)v0*512;          // panel: 128 x 512
  const int n_t = nact[t + 1];

  const int srow = tid >> 3;          // 0..31
  const int sphy = tid & 7;
  const int wuni = (tid >> 6) << 9;   // wave-uniform LDS base (elements): wave*512

  #define STAGE(gsrc, lbuf, kt)                                              \
    _Pragma("unroll")                                                        \
    for (int call = 0; call < 4; ++call){                                    \
      int row_ = call*32 + srow;                                             \
      gload_lds16(gsrc + (size_t)row_*512 + (kt)*64 + ((sphy ^ (row_ & 7)) << 3), \
                  lbuf + call*2048 + wuni);                                  \
    }

  const int lane = tid & 63;
  const int wv   = tid >> 6;
  const int wr   = wv >> 1, wc = wv & 1;
  const int fr   = lane & 15;
  const int hi   = lane >> 4;         // 0..3

  f32x4 acc[4][4];
  #pragma unroll
  for (int i = 0; i < 4; ++i)
    #pragma unroll
    for (int j = 0; j < 4; ++j)
      acc[i][j] = (f32x4){0.f,0.f,0.f,0.f};

  STAGE(Ag, Ab[0], 0)
  STAGE(Bg, Bb[0], 0)
  asm volatile("s_waitcnt vmcnt(0)" ::: "memory");
  __syncthreads();

  int cur = 0;
  for (int kt = 0; kt < 8; ++kt){
    if (kt < 7){
      STAGE(Ag, Ab[cur^1], kt+1)
      STAGE(Bg, Bb[cur^1], kt+1)
    }
    const unsigned short* As = Ab[cur];
    const unsigned short* Bs = Bb[cur];
    #pragma unroll
    for (int kk = 0; kk < 2; ++kk){
      const int c = kk*4 + hi;        // logical 16B slot within 64-elem row
      s16x8 af[4], bf[4];
      #pragma unroll
      for (int i = 0; i < 4; ++i){
        int row = wr*64 + i*16 + fr;
        af[i] = ld8(As + row*64 + ((c ^ (row & 7)) << 3));
      }
      #pragma unroll
      for (int j = 0; j < 4; ++j){
        int col = wc*64 + j*16 + fr;
        bf[j] = ld8(Bs + col*64 + ((c ^ (col & 7)) << 3));
      }
      #pragma unroll
      for (int i = 0; i < 4; ++i)
        #pragma unroll
        for (int j = 0; j < 4; ++j)
          acc[i][j] = MFMA16(af[i], bf[j], acc[i][j]);
    }
    asm volatile("s_waitcnt vmcnt(0)" ::: "memory");
    __syncthreads();
    cur ^= 1;
  }

  const int rr = hi * 4;
  #pragma unroll
  for (int j = 0; j < 4; ++j){
    int v = v0 + wc*64 + j*16 + fr;
    if (v >= 10000) continue;
    float bb = fcb[v];
    #pragma unroll
    for (int i = 0; i < 4; ++i){
      #pragma unroll
      for (int pp = 0; pp < 4; ++pp){
        int r = wr*64 + i*16 + rr + pp;
        out[(size_t)(r*19 + t)*10000 + v] = (r < n_t) ? (acc[i][j][pp] + bb) : 0.0f;
      }
    }
  }
  #undef STAGE
}

extern "C" void kernel_launch(void* const* d_in, const int* in_sizes, int n_in,
                              void* d_out, int out_size, void* d_ws, size_t ws_size,
                              hipStream_t stream) {
  const float* images   = (const float*)d_in[0];
  const int*   captions = (const int*)  d_in[1];
  const int*   length   = (const int*)  d_in[2];
  const float* emb      = (const float*)d_in[3];
  const float* W_ih     = (const float*)d_in[4];
  const float* W_hh     = (const float*)d_in[5];
  const float* b_ih     = (const float*)d_in[6];
  const float* b_hh     = (const float*)d_in[7];
  const float* fc_w     = (const float*)d_in[8];
  const float* fc_b     = (const float*)d_in[9];
  float* out = (float*)d_out;
  char*  ws  = (char*)d_ws;

  int*            sortp  = (int*)           (ws + 0);
  int*            nactp  = (int*)           (ws + 2048);
  float*          biasp  = (float*)         (ws + 4096);
  unsigned int*   cnt4k  = (unsigned int*)  (ws + 12288);     // claim[8] + flags[8][32]
  unsigned int*   claimc = cnt4k;                              // claimc + x*64
  unsigned int*   flags  = cnt4k + 512;                        // flags + x*64 + w
  unsigned short* hloc   = (unsigned short*)(ws + 16384);      // 8 x [21][16][512] bf16
  unsigned short* hseq   = (unsigned short*)(ws + 2768896);    // canonical 21 x 128 x 512 bf16
  unsigned short* xseq   = (unsigned short*)(ws + 5521408);    // 20 slots
  unsigned short* wihb   = (unsigned short*)(ws + 8142848);
  unsigned short* whhb   = (unsigned short*)(ws + 10240000);
  unsigned short* fcwb   = (unsigned short*)(ws + 12337152);   // 10112x512 bf16, ends ~22.7 MB

  k0_sort<<<1, 128, 0, stream>>>(length, captions, out, sortp, nactp, cnt4k);
  k1_convert<<<4096, 256, 0, stream>>>(images, captions, emb, W_ih, W_hh, b_ih, b_hh,
                                       fc_w, sortp, wihb, whhb, fcwb, biasp, xseq, hseq, hloc);
  lstm_chain<<<256, 256, 0, stream>>>(xseq, wihb, whhb, biasp, hseq, hloc,
                                      nactp, claimc, flags);
  fc_kernel<<<1520, 256, 0, stream>>>(hseq, fcwb, fc_b, nactp, out);
}

// Round 15
// 121.408 us; speedup vs baseline: 1.1792x; 1.0123x over previous
//
#include <hip/hip_runtime.h>

typedef float  f32x4 __attribute__((ext_vector_type(4)));
typedef short  s16x8 __attribute__((ext_vector_type(8)));
typedef unsigned short u16x4 __attribute__((ext_vector_type(4)));

#define MFMA16(a,b,c) __builtin_amdgcn_mfma_f32_16x16x32_bf16(a,b,c,0,0,0)

// sizes: B=128, S=20, T=19, E=H=512, G=2048, V=10000 (padded 10112)
#define PRED_ELEMS 24320000ull

__device__ __forceinline__ unsigned short f2bf(float f){
  unsigned u = __builtin_bit_cast(unsigned, f);
  u += 0x7fffu + ((u >> 16) & 1u);
  return (unsigned short)(u >> 16);
}
__device__ __forceinline__ float sigf(float x){ return 1.0f/(1.0f + __expf(-x)); }
__device__ __forceinline__ float tanh_(float x){
  x = fminf(15.0f, fmaxf(-15.0f, x));
  float e = __expf(2.0f*x);
  return (e - 1.0f) / (e + 1.0f);
}
__device__ __forceinline__ s16x8 ld8(const unsigned short* p){
  return *reinterpret_cast<const s16x8*>(p);
}
__device__ __forceinline__ void gload_lds16(const unsigned short* src, unsigned short* dst){
  __builtin_amdgcn_global_load_lds(
      (const __attribute__((address_space(1))) void*)src,
      (__attribute__((address_space(3))) void*)dst, 16, 0, 0);
}

// ---------------- K0: stable descending sort by length, tail outputs, counter init ----------------
__global__ void k0_sort(const int* __restrict__ length, const int* __restrict__ captions,
                        float* __restrict__ out, int* __restrict__ sortp,
                        int* __restrict__ nactp, unsigned int* __restrict__ cnt4k)
{
  __shared__ int sl[128], sdl[128], ssi[128];
  int tid = threadIdx.x;
  for (int k = tid; k < 1024; k += 128) cnt4k[k] = 0u;   // claim counters + arrival flags (4 KB)
  if (tid < 128) sl[tid] = length[tid];
  __syncthreads();
  if (tid < 128){
    int l = sl[tid];
    int rank = 0;
    for (int j = 0; j < 128; ++j){
      int lj = sl[j];
      rank += (lj > l) || (lj == l && j < tid);
    }
    sortp[rank] = tid;
    ssi[rank] = tid;   sdl[rank] = l - 1;
  }
  __syncthreads();
  if (tid < 20){
    int c = 0;
    for (int r = 0; r < 128; ++r) c += (sdl[r] >= tid);
    nactp[tid] = c;
  }
  if (tid < 128){
    const size_t P = PRED_ELEMS;
    int si = ssi[tid];
    for (int t = 0; t < 20; ++t) out[P + tid*20 + t] = (float)captions[si*20 + t];
    out[P + 2560 + tid] = (float)sdl[tid];
    out[P + 2688 + tid] = (float)si;
  }
}

// ---------------- K1: bf16 conversion / gather / zero-init (4-elem units) ----------------
__device__ __forceinline__ void cvt4(unsigned short* dst, const float* src, int u){
  f32x4 v = *reinterpret_cast<const f32x4*>(src + (size_t)u*4);
  u16x4 o;
  o[0]=f2bf(v[0]); o[1]=f2bf(v[1]); o[2]=f2bf(v[2]); o[3]=f2bf(v[3]);
  *reinterpret_cast<u16x4*>(dst + (size_t)u*4) = o;
}

__global__ void k1_convert(const float* __restrict__ images, const int* __restrict__ captions,
    const float* __restrict__ emb, const float* __restrict__ wih, const float* __restrict__ whh,
    const float* __restrict__ bih, const float* __restrict__ bhh, const float* __restrict__ fcw,
    const int* __restrict__ sortp,
    unsigned short* __restrict__ wihb, unsigned short* __restrict__ whhb,
    unsigned short* __restrict__ fcwb, float* __restrict__ biasp,
    unsigned short* __restrict__ xseq, unsigned short* __restrict__ hseq,
    unsigned short* __restrict__ hloc)
{
  const int U0 = 262144;      // W_ih  2048*512/4
  const int U1 = 262144;      // W_hh
  const int U2 = 1294336;     // fc_w padded 10112*512/4
  const int U3 = 512;         // bias 2048/4
  const int U4 = 327680;      // xseq 20*128*512/4
  const int U5 = 16384;       // hseq canonical slot 0 (zero h_init)
  const int U6 = 16384;       // hloc slot 0 per XCD (8 x 16 x 512)
  const int total = U0+U1+U2+U3+U4+U5+U6;
  for (int i = blockIdx.x*blockDim.x + threadIdx.x; i < total; i += gridDim.x*blockDim.x){
    int j = i;
    if (j < U0){ cvt4(wihb, wih, j); continue; }
    j -= U0;
    if (j < U1){ cvt4(whhb, whh, j); continue; }
    j -= U1;
    if (j < U2){
      int row = j >> 7;               // (j*4)/512
      if (row < 10000) cvt4(fcwb, fcw, j);
      else { u16x4 z = {0,0,0,0}; *reinterpret_cast<u16x4*>(fcwb + (size_t)j*4) = z; }
      continue;
    }
    j -= U2;
    if (j < U3){
      int e0 = j*4;
      for (int e = 0; e < 4; ++e) biasp[e0+e] = bih[e0+e] + bhh[e0+e];
      continue;
    }
    j -= U3;
    if (j < U4){
      int elem = j*4;
      int s = elem >> 16;             // /65536
      int rem = elem & 65535;
      int r = rem >> 9;
      int k = rem & 511;
      const float* src;
      if (s == 0) src = images + (size_t)sortp[r]*512 + k;
      else {
        int cap = captions[sortp[r]*20 + (s-1)];
        src = emb + (size_t)cap*512 + k;
      }
      f32x4 v = *reinterpret_cast<const f32x4*>(src);
      u16x4 o;
      o[0]=f2bf(v[0]); o[1]=f2bf(v[1]); o[2]=f2bf(v[2]); o[3]=f2bf(v[3]);
      *reinterpret_cast<u16x4*>(xseq + (size_t)j*4) = o;
      continue;
    }
    j -= U4;
    if (j < U5){ u16x4 z = {0,0,0,0}; *reinterpret_cast<u16x4*>(hseq + (size_t)j*4) = z; continue; }
    j -= U5;
    { // hloc slot 0 per XCD: hloc[x][0][16][512]
      int e0 = j*4;
      int x = e0 >> 13;               // /8192 (16*512)
      int rem = e0 & 8191;
      u16x4 z = {0,0,0,0};
      *reinterpret_cast<u16x4*>(hloc + (size_t)x*172032 + rem) = z;  // 21*16*512 per XCD
    }
  }
}

// ---------------- K3: XCD-local persistent LSTM chain (r14 structure, unchanged) ----------------
__global__ __launch_bounds__(256, 1) void lstm_chain(
    const unsigned short* __restrict__ xseq, const unsigned short* __restrict__ wih,
    const unsigned short* __restrict__ whh, const float* __restrict__ biasp,
    unsigned short* __restrict__ hseq, unsigned short* __restrict__ hloc,
    const int* __restrict__ nact, unsigned int* __restrict__ claimc,
    unsigned int* __restrict__ flags)
{
  const int tid = threadIdx.x;
  __shared__ int s_xw;
  __shared__ float pgh[4][4][16][17];       // 17.4 KB h-partials (kk, q, row, col)
  __shared__ float pgx[4][4][16][17];       // 17.4 KB x-partials for next step
  __shared__ unsigned char lds_pad[51200];  // pin LDS > 80 KB -> capacity-forced 1 block/CU
  asm volatile("" : : "v"(&lds_pad[tid & 127]) : "memory");

  if (tid == 0){
    unsigned xcc;
    asm volatile("s_getreg_b32 %0, hwreg(20, 0, 4)" : "=s"(xcc));  // HW_REG_XCC_ID
    int x = (int)(xcc & 7u);
    unsigned slot = __hip_atomic_fetch_add(claimc + x*64, 1u,
                      __ATOMIC_RELAXED, __HIP_MEMORY_SCOPE_AGENT);
    s_xw = (x << 8) | (int)(slot & 255u);
  }
  __syncthreads();
  const int x = s_xw >> 8;
  const int w = s_xw & 255;
  if (w >= 32) return;
  const int R0 = x*16;
  const int C0 = w*16;
  unsigned int* myflags = flags + x*64;     // 32 words used per XCD, 256B stride

  const int lane = tid & 63;
  const int kk   = tid >> 6;                 // wave = k-quarter (128 of 512)
  const int fr   = lane & 15;
  const int fkq  = (lane >> 4) * 8;
  const int rr   = (lane >> 4) * 4;

  // step-invariant B fragments in registers: [gate][k-chunk]
  s16x8 BI[4][4], BH[4][4];
  #pragma unroll
  for (int q = 0; q < 4; ++q)
    #pragma unroll
    for (int i = 0; i < 4; ++i){
      size_t off = (size_t)(q*512 + C0 + fr)*512 + kk*128 + i*32 + fkq;
      BI[q][i] = ld8(wih + off);
      BH[q][i] = ld8(whh + off);
    }

  unsigned short* hl = hloc + (size_t)x*172032;   // [21][16][512]
  const int prow = tid >> 4;
  const int pcol = tid & 15;
  const float bz0 = biasp[       C0 + pcol];
  const float bz1 = biasp[ 512 + C0 + pcol];
  const float bz2 = biasp[1024 + C0 + pcol];
  const float bz3 = biasp[1536 + C0 + pcol];
  float creg = 0.f;

  // prologue: x-partials for step 0
  {
    s16x8 ax[4];
    #pragma unroll
    for (int i = 0; i < 4; ++i)
      ax[i] = ld8(xseq + (R0 + fr)*512 + kk*128 + i*32 + fkq);
    #pragma unroll
    for (int q = 0; q < 4; ++q){
      f32x4 accx = (f32x4){0.f,0.f,0.f,0.f};
      #pragma unroll
      for (int i = 0; i < 4; ++i)
        accx = MFMA16(ax[i], BI[q][i], accx);
      #pragma unroll
      for (int p = 0; p < 4; ++p)
        pgx[kk][q][rr + p][fr] = accx[p];
    }
  }
  __syncthreads();

  for (int s = 0; s < 20; ++s){
    if (R0 >= nact[s]) break;
    const unsigned short* hp = hl + (size_t)s*8192;

    // h-part: 16 loads, 16 MFMAs, B from registers
    s16x8 ah[4];
    #pragma unroll
    for (int i = 0; i < 4; ++i)
      ah[i] = ld8(hp + fr*512 + kk*128 + i*32 + fkq);
    #pragma unroll
    for (int q = 0; q < 4; ++q){
      f32x4 acch = (f32x4){0.f,0.f,0.f,0.f};
      #pragma unroll
      for (int i = 0; i < 4; ++i)
        acch = MFMA16(ah[i], BH[q][i], acch);
      #pragma unroll
      for (int p = 0; p < 4; ++p)
        pgh[kk][q][rr + p][fr] = acch[p];
    }
    __syncthreads();   // (A) pgh ready; pgx from previous window ready

    unsigned short hb;
    {
      float iv = pgh[0][0][prow][pcol] + pgh[1][0][prow][pcol]
               + pgh[2][0][prow][pcol] + pgh[3][0][prow][pcol]
               + pgx[0][0][prow][pcol] + pgx[1][0][prow][pcol]
               + pgx[2][0][prow][pcol] + pgx[3][0][prow][pcol] + bz0;
      float fv = pgh[0][1][prow][pcol] + pgh[1][1][prow][pcol]
               + pgh[2][1][prow][pcol] + pgh[3][1][prow][pcol]
               + pgx[0][1][prow][pcol] + pgx[1][1][prow][pcol]
               + pgx[2][1][prow][pcol] + pgx[3][1][prow][pcol] + bz1;
      float gv = pgh[0][2][prow][pcol] + pgh[1][2][prow][pcol]
               + pgh[2][2][prow][pcol] + pgh[3][2][prow][pcol]
               + pgx[0][2][prow][pcol] + pgx[1][2][prow][pcol]
               + pgx[2][2][prow][pcol] + pgx[3][2][prow][pcol] + bz2;
      float ov = pgh[0][3][prow][pcol] + pgh[1][3][prow][pcol]
               + pgh[2][3][prow][pcol] + pgh[3][3][prow][pcol]
               + pgx[0][3][prow][pcol] + pgx[1][3][prow][pcol]
               + pgx[2][3][prow][pcol] + pgx[3][3][prow][pcol] + bz3;
      creg = sigf(fv)*creg + sigf(iv)*tanh_(gv);
      float h = sigf(ov)*tanh_(creg);
      hb = f2bf(h);
      hl[(size_t)(s+1)*8192 + prow*512 + C0 + pcol] = hb;   // XCD-local publish
    }
    __syncthreads();   // (B) hl drained into this XCD's L2; pgx consumed

    // canonical mirror for fc — off the critical path (consumed after dispatch release)
    hseq[(size_t)(s+1)*65536 + (R0 + prow)*512 + C0 + pcol] = hb;

    if (s < 19 && nact[s+1] > R0){
      const unsigned tgt = (unsigned)(s + 1);
      if (tid == 0)
        __hip_atomic_store(&myflags[w], tgt, __ATOMIC_RELAXED, __HIP_MEMORY_SCOPE_AGENT);

      // x-partials for step s+1 — useful work inside the barrier window
      {
        const unsigned short* xp = xseq + (size_t)(s+1)*65536;
        s16x8 ax[4];
        #pragma unroll
        for (int i = 0; i < 4; ++i)
          ax[i] = ld8(xp + (R0 + fr)*512 + kk*128 + i*32 + fkq);
        #pragma unroll
        for (int q = 0; q < 4; ++q){
          f32x4 accx = (f32x4){0.f,0.f,0.f,0.f};
          #pragma unroll
          for (int i = 0; i < 4; ++i)
            accx = MFMA16(ax[i], BI[q][i], accx);
          #pragma unroll
          for (int p = 0; p < 4; ++p)
            pgx[kk][q][rr + p][fr] = accx[p];
        }
      }

      if (tid < 64){
        long guard = 0;
        for (;;){
          bool ok = true;
          if (tid < 32)
            ok = (__hip_atomic_load(&myflags[tid], __ATOMIC_RELAXED,
                                    __HIP_MEMORY_SCOPE_AGENT) >= tgt);
          if (__all(ok) || ++guard > (1L << 20)) break;
          __builtin_amdgcn_s_sleep(1);
        }
      }
      __syncthreads();   // (C) release
    }
  }
}

// ---------------- K4: batched FC, gload_lds dbuf + XOR swizzle + float4 epilogue ----------------
// Grid 1520: x=b&7 (XCD), slot=b>>3; t=slot%19, p=x+8*(slot/19). Tile 128x128, BK=64.
// Epilogue: stage the result tile through the (now-free) 64 KB staging LDS, then each
// wave stores 32 rows as float4 runs (16 dwordx4/thread, 128B-contiguous segments) —
// replaces 64 scalar dword stores/thread.
__global__ __launch_bounds__(256) void fc_kernel(
    const unsigned short* __restrict__ hseq, const unsigned short* __restrict__ fcwb,
    const float* __restrict__ fcb, const int* __restrict__ nact,
    float* __restrict__ out)
{
  const int b    = blockIdx.x;
  const int x    = b & 7;
  const int slot = b >> 3;
  const int t    = slot % 19;
  const int p    = x + 8*(slot/19);
  if (p >= 79) return;
  const int v0   = p * 128;
  const int tid  = threadIdx.x;

  __shared__ unsigned short arena[2][2][8192];   // [buf][A=0/B=1][8192] = 64 KB total
  #define Ab(c) (&arena[c][0][0])
  #define Bb(c) (&arena[c][1][0])

  const unsigned short* Ag = hseq + (size_t)(t + 2)*65536;   // h_{t+1}: 128 x 512
  const unsigned short* Bg = fcwb + (size_t)v0*512;          // panel: 128 x 512
  const int n_t = nact[t + 1];

  const int srow = tid >> 3;          // 0..31
  const int sphy = tid & 7;
  const int wuni = (tid >> 6) << 9;   // wave-uniform LDS base (elements): wave*512

  #define STAGE(gsrc, lbuf, kt)                                              \
    _Pragma("unroll")                                                        \
    for (int call = 0; call < 4; ++call){                                    \
      int row_ = call*32 + srow;                                             \
      gload_lds16(gsrc + (size_t)row_*512 + (kt)*64 + ((sphy ^ (row_ & 7)) << 3), \
                  lbuf + call*2048 + wuni);                                  \
    }

  const int lane = tid & 63;
  const int wv   = tid >> 6;
  const int wr   = wv >> 1, wc = wv & 1;
  const int fr   = lane & 15;
  const int hi   = lane >> 4;         // 0..3

  f32x4 acc[4][4];
  #pragma unroll
  for (int i = 0; i < 4; ++i)
    #pragma unroll
    for (int j = 0; j < 4; ++j)
      acc[i][j] = (f32x4){0.f,0.f,0.f,0.f};

  STAGE(Ag, Ab(0), 0)
  STAGE(Bg, Bb(0), 0)
  asm volatile("s_waitcnt vmcnt(0)" ::: "memory");
  __syncthreads();

  int cur = 0;
  for (int kt = 0; kt < 8; ++kt){
    if (kt < 7){
      STAGE(Ag, Ab(cur^1), kt+1)
      STAGE(Bg, Bb(cur^1), kt+1)
    }
    const unsigned short* As = Ab(cur);
    const unsigned short* Bs = Bb(cur);
    #pragma unroll
    for (int kk = 0; kk < 2; ++kk){
      const int c = kk*4 + hi;        // logical 16B slot within 64-elem row
      s16x8 af[4], bf[4];
      #pragma unroll
      for (int i = 0; i < 4; ++i){
        int row = wr*64 + i*16 + fr;
        af[i] = ld8(As + row*64 + ((c ^ (row & 7)) << 3));
      }
      #pragma unroll
      for (int j = 0; j < 4; ++j){
        int col = wc*64 + j*16 + fr;
        bf[j] = ld8(Bs + col*64 + ((c ^ (col & 7)) << 3));
      }
      #pragma unroll
      for (int i = 0; i < 4; ++i)
        #pragma unroll
        for (int j = 0; j < 4; ++j)
          acc[i][j] = MFMA16(af[i], bf[j], acc[i][j]);
    }
    asm volatile("s_waitcnt vmcnt(0)" ::: "memory");
    __syncthreads();
    cur ^= 1;
  }

  // ---- epilogue: stage tile into LDS (f32 [128][128]) with bias + masks applied ----
  float* lgout = reinterpret_cast<float*>(arena);
  const int rr = hi * 4;
  #pragma unroll
  for (int j = 0; j < 4; ++j){
    int colv = wc*64 + j*16 + fr;                 // 0..127 within tile
    int v = v0 + colv;
    float bb = (v < 10000) ? fcb[v] : 0.f;
    #pragma unroll
    for (int i = 0; i < 4; ++i){
      int r = wr*64 + i*16 + rr;
      #pragma unroll
      for (int pp = 0; pp < 4; ++pp){
        float val = ((r + pp) < n_t) ? (acc[i][j][pp] + bb) : 0.0f;
        lgout[(r + pp)*128 + colv] = val;
      }
    }
  }
  __syncthreads();

  // ---- store: wave wv -> rows [wv*32, +32), 2 rows per iteration, float4 per lane ----
  {
    const int half = lane >> 5;            // 0..1
    const int ch   = lane & 31;            // float4 chunk within row
    const int v    = v0 + ch*4;
    if (v < 10000){
      #pragma unroll
      for (int k2 = 0; k2 < 16; ++k2){
        int r = wv*32 + k2*2 + half;
        f32x4 val = *reinterpret_cast<const f32x4*>(&lgout[r*128 + ch*4]);
        *reinterpret_cast<f32x4*>(&out[(size_t)(r*19 + t)*10000 + v]) = val;
      }
    }
  }
  #undef STAGE
  #undef Ab
  #undef Bb
}

extern "C" void kernel_launch(void* const* d_in, const int* in_sizes, int n_in,
                              void* d_out, int out_size, void* d_ws, size_t ws_size,
                              hipStream_t stream) {
  const float* images   = (const float*)d_in[0];
  const int*   captions = (const int*)  d_in[1];
  const int*   length   = (const int*)  d_in[2];
  const float* emb      = (const float*)d_in[3];
  const float* W_ih     = (const float*)d_in[4];
  const float* W_hh     = (const float*)d_in[5];
  const float* b_ih     = (const float*)d_in[6];
  const float* b_hh     = (const float*)d_in[7];
  const float* fc_w     = (const float*)d_in[8];
  const float* fc_b     = (const float*)d_in[9];
  float* out = (float*)d_out;
  char*  ws  = (char*)d_ws;

  int*            sortp  = (int*)           (ws + 0);
  int*            nactp  = (int*)           (ws + 2048);
  float*          biasp  = (float*)         (ws + 4096);
  unsigned int*   cnt4k  = (unsigned int*)  (ws + 12288);     // claim[8] + flags[8][32]
  unsigned int*   claimc = cnt4k;                              // claimc + x*64
  unsigned int*   flags  = cnt4k + 512;                        // flags + x*64 + w
  unsigned short* hloc   = (unsigned short*)(ws + 16384);      // 8 x [21][16][512] bf16
  unsigned short* hseq   = (unsigned short*)(ws + 2768896);    // canonical 21 x 128 x 512 bf16
  unsigned short* xseq   = (unsigned short*)(ws + 5521408);    // 20 slots
  unsigned short* wihb   = (unsigned short*)(ws + 8142848);
  unsigned short* whhb   = (unsigned short*)(ws + 10240000);
  unsigned short* fcwb   = (unsigned short*)(ws + 12337152);   // 10112x512 bf16, ends ~22.7 MB

  k0_sort<<<1, 128, 0, stream>>>(length, captions, out, sortp, nactp, cnt4k);
  k1_convert<<<4096, 256, 0, stream>>>(images, captions, emb, W_ih, W_hh, b_ih, b_hh,
                                       fc_w, sortp, wihb, whhb, fcwb, biasp, xseq, hseq, hloc);
  lstm_chain<<<256, 256, 0, stream>>>(xseq, wihb, whhb, biasp, hseq, hloc,
                                      nactp, claimc, flags);
  fc_kernel<<<1520, 256, 0, stream>>>(hseq, fcwb, fc_b, nactp, out);
}